// Round 5
// baseline (156.835 us; speedup 1.0000x reference)
//
#include <hip/hip_runtime.h>
#include <hip/hip_bf16.h>

typedef _Float16 f16;
typedef _Float16 f16x4 __attribute__((ext_vector_type(4)));
typedef _Float16 f16x8 __attribute__((ext_vector_type(8)));
typedef float f32x4 __attribute__((ext_vector_type(4)));

#define HH 96
#define WW 96
#define HWs 9216
#define BN_EPS 1e-5f

// ---- workspace layout (byte offsets) ----
#define OFF_ACT1 0u            // [2][9216][128] f16 : value        4,718,592
#define OFF_ACT2 4718592u      // [2][9216][128] f16 : key|query    4,718,592

// ---------------- conv12: fused transpose + stage1 (256 couts) + stage2, weights converted inline ----------------
// 32-px tile, 4 waves. Wave w owns stage-1 couts [64w, 64w+64):
//   w=0,1 -> value -> act1 global; w=2 -> k1 -> LDS; w=3 -> q1 -> LDS.
// Then stage2: wave w -> (sel = w>>1 ? query : key), couts2 (w&1)*32..+32, from LDS k1/q1.
__global__ __launch_bounds__(256) void conv12(
    const float* __restrict__ x,
    const float* __restrict__ fv_w, const float* __restrict__ fk_w1, const float* __restrict__ fq_w1,
    const float* __restrict__ fk_w2, const float* __restrict__ fq_w2,
    const float* __restrict__ fv_b,
    const float* __restrict__ fk_b1, const float* __restrict__ fk_bn1,
    const float* __restrict__ fq_b1, const float* __restrict__ fq_bn1,
    const float* __restrict__ fk_b2, const float* __restrict__ fk_bn2,
    const float* __restrict__ fq_b2, const float* __restrict__ fq_bn2,
    f16* __restrict__ act1, f16* __restrict__ act2)
{
  __shared__ f16 As[32 * 40];        // 2,560 B  x-tile transposed [px][k]
  __shared__ f16 Bs[256 * 40];       // 20,480 B W1 k-slice (f16, converted inline)
  __shared__ f16 kqs[2][32 * 72];    // 9,216 B  k1 / q1 (relu'd)
  const int tid = threadIdx.x;
  const int l = tid & 63, w = tid >> 6;
  const int bb = blockIdx.y;
  const int p0 = blockIdx.x * 32;
  const int lrow = l & 15, lk = (l >> 4) * 8;

  f32x4 acc[2][4];
#pragma unroll
  for (int i = 0; i < 2; i++)
#pragma unroll
    for (int j = 0; j < 4; j++) acc[i][j] = (f32x4){0.f, 0.f, 0.f, 0.f};

  const int spx = tid & 31, skg = tid >> 5;   // staging: px, k-quad
#pragma unroll 1
  for (int ks = 0; ks < 8; ks++) {
    // stage A: x NCHW f32 -> As[px][k] f16
    f16x4 av;
#pragma unroll
    for (int j = 0; j < 4; j++)
      av[j] = (f16)x[((size_t)bb * 256 + ks * 32 + skg * 4 + j) * HWs + p0 + spx];
    *(f16x4*)&As[spx * 40 + skg * 4] = av;
    // stage B: W1 rows 0..255 k-chunk, f32 sources converted inline (it selects source uniformly)
#pragma unroll
    for (int it = 0; it < 4; it++) {
      int tt = it * 256 + tid;
      int row = tt >> 2, seg = tt & 3;
      const float* srcp;
      if (it < 2)      srcp = fv_w  + (size_t)row * 256;
      else if (it == 2) srcp = fk_w1 + (size_t)(row - 128) * 256;
      else              srcp = fq_w1 + (size_t)(row - 192) * 256;
      float4 u0 = *(const float4*)&srcp[ks * 32 + seg * 8];
      float4 u1 = *(const float4*)&srcp[ks * 32 + seg * 8 + 4];
      f16x8 h = {(f16)u0.x, (f16)u0.y, (f16)u0.z, (f16)u0.w,
                 (f16)u1.x, (f16)u1.y, (f16)u1.z, (f16)u1.w};
      *(f16x8*)&Bs[row * 40 + seg * 8] = h;
    }
    __syncthreads();
    f16x8 a[2], b[4];
#pragma unroll
    for (int mi = 0; mi < 2; mi++) a[mi] = *(const f16x8*)&As[(mi * 16 + lrow) * 40 + lk];
#pragma unroll
    for (int nj = 0; nj < 4; nj++) b[nj] = *(const f16x8*)&Bs[(w * 64 + nj * 16 + lrow) * 40 + lk];
#pragma unroll
    for (int mi = 0; mi < 2; mi++)
#pragma unroll
      for (int nj = 0; nj < 4; nj++)
        acc[mi][nj] = __builtin_amdgcn_mfma_f32_16x16x32_f16(a[mi], b[nj], acc[mi][nj], 0, 0, 0);
    __syncthreads();
  }

  // stage-1 epilogue: BN fold computed inline (wave-uniform branches)
#pragma unroll
  for (int nj = 0; nj < 4; nj++) {
    int cout = w * 64 + nj * 16 + lrow;
    float s, t;
    if (w < 2) { s = 1.0f; t = fv_b[cout]; }
    else {
      int j = nj * 16 + lrow;
      const float* bn = (w == 2) ? fk_bn1 : fq_bn1;
      const float* bs = (w == 2) ? fk_b1 : fq_b1;
      float g = bn[j], be = bn[64 + j], m = bn[128 + j], v = bn[192 + j];
      s = g * rsqrtf(v + BN_EPS); t = (bs[j] - m) * s + be;
    }
#pragma unroll
    for (int mi = 0; mi < 2; mi++)
#pragma unroll
      for (int r = 0; r < 4; r++) {
        int px = mi * 16 + (l >> 4) * 4 + r;
        float v = acc[mi][nj][r] * s + t;
        if (w < 2) {
          act1[((size_t)bb * HWs + p0 + px) * 128 + cout] = (f16)v;
        } else {
          kqs[w - 2][px * 72 + (nj * 16 + lrow)] = (f16)fmaxf(v, 0.f);
        }
      }
  }
  __syncthreads();

  // stage2: K=64 from LDS k1/q1, W2 read f32 + converted inline
  const int sel = w >> 1, half = w & 1;
  const float* W2s = sel ? fq_w2 : fk_w2;
  f32x4 acc2[2][2];
#pragma unroll
  for (int i = 0; i < 2; i++)
#pragma unroll
    for (int j = 0; j < 2; j++) acc2[i][j] = (f32x4){0.f, 0.f, 0.f, 0.f};
#pragma unroll
  for (int ks = 0; ks < 2; ks++) {
    f16x8 a2[2], b2[2];
#pragma unroll
    for (int mi = 0; mi < 2; mi++)
      a2[mi] = *(const f16x8*)&kqs[sel][(mi * 16 + lrow) * 72 + ks * 32 + lk];
#pragma unroll
    for (int nj = 0; nj < 2; nj++) {
      const float* wp = &W2s[(size_t)(half * 32 + nj * 16 + lrow) * 64 + ks * 32 + lk];
      float4 u0 = *(const float4*)&wp[0];
      float4 u1 = *(const float4*)&wp[4];
      b2[nj] = (f16x8){(f16)u0.x, (f16)u0.y, (f16)u0.z, (f16)u0.w,
                       (f16)u1.x, (f16)u1.y, (f16)u1.z, (f16)u1.w};
    }
#pragma unroll
    for (int mi = 0; mi < 2; mi++)
#pragma unroll
      for (int nj = 0; nj < 2; nj++)
        acc2[mi][nj] = __builtin_amdgcn_mfma_f32_16x16x32_f16(a2[mi], b2[nj], acc2[mi][nj], 0, 0, 0);
  }
#pragma unroll
  for (int nj = 0; nj < 2; nj++) {
    int j2 = half * 32 + nj * 16 + lrow;
    int c2 = sel * 64 + j2;
    const float* bn = sel ? fq_bn2 : fk_bn2;
    const float* bs = sel ? fq_b2 : fk_b2;
    float g = bn[j2], be = bn[64 + j2], m = bn[128 + j2], v = bn[192 + j2];
    float s = g * rsqrtf(v + BN_EPS), t = (bs[j2] - m) * s + be;
#pragma unroll
    for (int mi = 0; mi < 2; mi++)
#pragma unroll
      for (int r = 0; r < 4; r++) {
        int px = mi * 16 + (l >> 4) * 4 + r;
        float vv = fmaxf(acc2[mi][nj][r] * s + t, 0.f);
        act2[((size_t)bb * HWs + p0 + px) * 128 + c2] = (f16)vv;
      }
  }
}

// ---------------- attn_final: 8x4 pixel tile (576 blocks) + fused output projection ----------------
__global__ __launch_bounds__(256) void attn_final(const f16* __restrict__ act1,
                                                  const f16* __restrict__ act2,
                                                  const float* __restrict__ W_w,
                                                  const float* __restrict__ W_b,
                                                  float* __restrict__ out)
{
  __shared__ f16 Qs[32 * 72];        // 4,608 B
  __shared__ f16 Ks[144 * 72];       // 20,736 B (rows 140-143 zeroed)
  __shared__ f16 Vs[144 * 136];      // 39,168 B (reused as ctx after PV)
  __shared__ float Ps[32 * 52];      // 6,656 B
  const int tid = threadIdx.x;
  const int l = tid & 63, w = tid >> 6;
  const int bb = blockIdx.z;
  const int x0 = blockIdx.x * 8, y0 = blockIdx.y * 4;
  const f16* a2 = act2 + (size_t)bb * HWs * 128;
  const f16* a1 = act1 + (size_t)bb * HWs * 128;
  const int lrow = l & 15, lk = (l >> 4) * 8;

  // stage Q (act2 ch 64..127): 32 px x 8 segs = 256 -> one per thread
  {
    int q = tid >> 3, seg = tid & 7;
    int gp = (y0 + (q >> 3)) * WW + x0 + (q & 7);
    *(f16x8*)&Qs[q * 72 + seg * 8] = *(const f16x8*)&a2[(size_t)gp * 128 + 64 + seg * 8];
  }
  // stage K (act2 ch 0..63): 144 halo rows x 8 segs, zero OOB + pad rows
  for (int t = tid; t < 1152; t += 256) {
    int kk = t >> 3, seg = t & 7;
    int ky = (kk * 4682) >> 16, kx = kk - 14 * ky;
    int gy = y0 - 3 + ky, gx = x0 - 3 + kx;
    f16x8 v = {(f16)0, (f16)0, (f16)0, (f16)0, (f16)0, (f16)0, (f16)0, (f16)0};
    if (kk < 140 && (unsigned)gy < (unsigned)HH && (unsigned)gx < (unsigned)WW)
      v = *(const f16x8*)&a2[((size_t)(gy * WW + gx)) * 128 + seg * 8];
    *(f16x8*)&Ks[kk * 72 + seg * 8] = v;
  }
  // stage V (act1 ch 0..127): 144 rows x 16 segs = 2304 -> 9 iters
  for (int t = tid; t < 2304; t += 256) {
    int kk = t >> 4, seg = t & 15;
    int ky = (kk * 4682) >> 16, kx = kk - 14 * ky;
    int gy = y0 - 3 + ky, gx = x0 - 3 + kx;
    f16x8 v = {(f16)0, (f16)0, (f16)0, (f16)0, (f16)0, (f16)0, (f16)0, (f16)0};
    if (kk < 140 && (unsigned)gy < (unsigned)HH && (unsigned)gx < (unsigned)WW)
      v = *(const f16x8*)&a1[((size_t)(gy * WW + gx)) * 128 + seg * 8];
    *(f16x8*)&Vs[kk * 136 + seg * 8] = v;
  }
  __syncthreads();

  // QK on waves 0,1: wave w owns q-rows 16w..16w+15 (complete rows -> local softmax)
  if (w < 2) {
    f32x4 sc[9];
#pragma unroll
    for (int nj = 0; nj < 9; nj++) sc[nj] = (f32x4){0.f, 0.f, 0.f, 0.f};
#pragma unroll
    for (int ks = 0; ks < 2; ks++) {
      f16x8 aq = *(const f16x8*)&Qs[(w * 16 + lrow) * 72 + ks * 32 + lk];
#pragma unroll
      for (int nj = 0; nj < 9; nj++) {
        f16x8 bk = *(const f16x8*)&Ks[(nj * 16 + lrow) * 72 + ks * 32 + lk];
        sc[nj] = __builtin_amdgcn_mfma_f32_16x16x32_f16(aq, bk, sc[nj], 0, 0, 0);
      }
    }
    // mask non-window cols (image-OOB stays 0 via zero-staged K = reference semantics)
    const int r0 = w * 16 + (l >> 4) * 4;
#pragma unroll
    for (int nj = 0; nj < 9; nj++) {
      int c = nj * 16 + lrow;
      int ky = (c * 4682) >> 16, kx = c - 14 * ky;
#pragma unroll
      for (int r = 0; r < 4; r++) {
        int row = r0 + r;
        int qy = (row >> 3), qx = row & 7;
        bool valid = (c < 140) && ((unsigned)(ky - qy) < 7u) && ((unsigned)(kx - qx) < 7u);
        if (!valid) sc[nj][r] = -1e30f;
      }
    }
    // softmax per q-row (row spread over 16-lane group x 9 frags)
    float mx[4], sm[4], inv[4];
#pragma unroll
    for (int r = 0; r < 4; r++) {
      mx[r] = -1e30f;
#pragma unroll
      for (int nj = 0; nj < 9; nj++) mx[r] = fmaxf(mx[r], sc[nj][r]);
    }
#pragma unroll
    for (int off = 1; off < 16; off <<= 1)
#pragma unroll
      for (int r = 0; r < 4; r++) mx[r] = fmaxf(mx[r], __shfl_xor(mx[r], off));
#pragma unroll
    for (int r = 0; r < 4; r++) sm[r] = 0.f;
#pragma unroll
    for (int nj = 0; nj < 9; nj++)
#pragma unroll
      for (int r = 0; r < 4; r++) {
        float e = __expf(sc[nj][r] - mx[r]);
        sc[nj][r] = e; sm[r] += e;
      }
#pragma unroll
    for (int off = 1; off < 16; off <<= 1)
#pragma unroll
      for (int r = 0; r < 4; r++) sm[r] += __shfl_xor(sm[r], off);
#pragma unroll
    for (int r = 0; r < 4; r++) inv[r] = 1.0f / sm[r];
    // scatter valid probs into Ps[q][49]
#pragma unroll
    for (int nj = 0; nj < 9; nj++) {
      int c = nj * 16 + lrow;
      int ky = (c * 4682) >> 16, kx = c - 14 * ky;
#pragma unroll
      for (int r = 0; r < 4; r++) {
        int row = r0 + r;
        int qy = (row >> 3), qx = row & 7;
        int dy = ky - qy, dx = kx - qx;
        if (c < 140 && ((unsigned)dy < 7u) && ((unsigned)dx < 7u))
          Ps[row * 52 + dy * 7 + dx] = sc[nj][r] * inv[r];
      }
    }
  }
  __syncthreads();

  // PV (VALU, f32 acc): 8 threads/px, 16 ch each
  const int q = tid >> 3, c8 = tid & 7;
  const int qy = q >> 3, qx = q & 7;
  const int ch0 = c8 * 16;
  float acc[16];
#pragma unroll
  for (int i = 0; i < 16; i++) acc[i] = 0.f;
#pragma unroll
  for (int dy = 0; dy < 7; dy++)
#pragma unroll
    for (int dx = 0; dx < 7; dx++) {
      float p = Ps[q * 52 + dy * 7 + dx];
      int kk = (qy + dy) * 14 + qx + dx;
      const f16* vp = &Vs[kk * 136 + ch0];
      f16x8 v0 = *(const f16x8*)&vp[0];
      f16x8 v1 = *(const f16x8*)&vp[8];
#pragma unroll
      for (int j = 0; j < 8; j++) {
        acc[j] += (float)v0[j] * p;
        acc[8 + j] += (float)v1[j] * p;
      }
    }
  __syncthreads();   // all PV reads of Vs complete before ctx overwrite

  // ctx -> LDS (reuse Vs)
  {
    f16x8 o0, o1;
#pragma unroll
    for (int j = 0; j < 8; j++) { o0[j] = (f16)acc[j]; o1[j] = (f16)acc[8 + j]; }
    *(f16x8*)&Vs[q * 136 + ch0] = o0;
    *(f16x8*)&Vs[q * 136 + ch0 + 8] = o1;
  }
  __syncthreads();

  // final projection: wave w -> couts [64w,64w+64); A = W_w f32 (inline cvt), B = ctx (LDS)
  f32x4 fac[4][2];
#pragma unroll
  for (int i = 0; i < 4; i++)
#pragma unroll
    for (int j = 0; j < 2; j++) fac[i][j] = (f32x4){0.f, 0.f, 0.f, 0.f};
#pragma unroll
  for (int ks = 0; ks < 4; ks++) {
    f16x8 a3[4], b3[2];
#pragma unroll
    for (int mi = 0; mi < 4; mi++) {
      const float* wp = &W_w[(size_t)(w * 64 + mi * 16 + lrow) * 128 + ks * 32 + lk];
      float4 u0 = *(const float4*)&wp[0];
      float4 u1 = *(const float4*)&wp[4];
      a3[mi] = (f16x8){(f16)u0.x, (f16)u0.y, (f16)u0.z, (f16)u0.w,
                       (f16)u1.x, (f16)u1.y, (f16)u1.z, (f16)u1.w};
    }
#pragma unroll
    for (int nj = 0; nj < 2; nj++)
      b3[nj] = *(const f16x8*)&Vs[(nj * 16 + lrow) * 136 + ks * 32 + lk];
#pragma unroll
    for (int mi = 0; mi < 4; mi++)
#pragma unroll
      for (int nj = 0; nj < 2; nj++)
        fac[mi][nj] = __builtin_amdgcn_mfma_f32_16x16x32_f16(a3[mi], b3[nj], fac[mi][nj], 0, 0, 0);
  }
#pragma unroll
  for (int mi = 0; mi < 4; mi++)
#pragma unroll
    for (int r = 0; r < 4; r++) {
      int cout = w * 64 + mi * 16 + (l >> 4) * 4 + r;
      float bias = W_b[cout];
#pragma unroll
      for (int nj = 0; nj < 2; nj++) {
        int px = nj * 16 + lrow;
        int gp = (y0 + (px >> 3)) * WW + x0 + (px & 7);
        out[((size_t)bb * 256 + cout) * HWs + gp] = fac[mi][nj][r] + bias;
      }
    }
}

extern "C" void kernel_launch(void* const* d_in, const int* in_sizes, int n_in,
                              void* d_out, int out_size, void* d_ws, size_t ws_size,
                              hipStream_t stream) {
  (void)in_sizes; (void)n_in; (void)out_size; (void)ws_size;
  const float* x      = (const float*)d_in[0];
  const float* fk_w1  = (const float*)d_in[1];
  const float* fk_b1  = (const float*)d_in[2];
  const float* fk_bn1 = (const float*)d_in[3];
  const float* fk_w2  = (const float*)d_in[4];
  const float* fk_b2  = (const float*)d_in[5];
  const float* fk_bn2 = (const float*)d_in[6];
  const float* fq_w1  = (const float*)d_in[7];
  const float* fq_b1  = (const float*)d_in[8];
  const float* fq_bn1 = (const float*)d_in[9];
  const float* fq_w2  = (const float*)d_in[10];
  const float* fq_b2  = (const float*)d_in[11];
  const float* fq_bn2 = (const float*)d_in[12];
  const float* fv_w   = (const float*)d_in[13];
  const float* fv_b   = (const float*)d_in[14];
  const float* W_w    = (const float*)d_in[15];
  const float* W_b    = (const float*)d_in[16];
  char* wsb = (char*)d_ws;
  float* out = (float*)d_out;

  f16* act1 = (f16*)(wsb + OFF_ACT1);
  f16* act2 = (f16*)(wsb + OFF_ACT2);

  conv12<<<dim3(288, 2), dim3(256), 0, stream>>>(
      x, fv_w, fk_w1, fq_w1, fk_w2, fq_w2,
      fv_b, fk_b1, fk_bn1, fq_b1, fq_bn1,
      fk_b2, fk_bn2, fq_b2, fq_bn2, act1, act2);

  attn_final<<<dim3(12, 24, 2), dim3(256), 0, stream>>>(act1, act2, W_w, W_b, out);
}